// Round 11
// baseline (142.255 us; speedup 1.0000x reference)
//
#include <hip/hip_runtime.h>
#include <hip/hip_bf16.h>
#include <stdint.h>
#include <stddef.h>

#define NROWS 8192
#define DDIM  512              // floats per input row; ALSO bytes per fp8 row
#define TILE  128
#define BKB   64               // fp8 K-bytes per LDS stage (8 stages, double-buffered)
#define NSTG  (DDIM / BKB)     // 8
#define NBLK  (NROWS / TILE)   // 64

static_assert(NBLK == 64, "bj extraction assumes 64 col-blocks");

typedef float f32x4 __attribute__((ext_vector_type(4)));
typedef long  v2l  __attribute__((ext_vector_type(2)));   // one 16-B LDS read

// async global->LDS, 16B per lane; LDS dest is wave-uniform base + lane*16
__device__ __forceinline__ void async_copy16(const void* g, void* l) {
    __builtin_amdgcn_global_load_lds(
        (const __attribute__((address_space(1))) uint32_t*)g,
        (__attribute__((address_space(3))) uint32_t*)l,
        16, 0, 0);
}

// -------- prep: zero accumulators + normalize both matrices to fp8 e4m3 --------
// grid = 4096: blocks [0,2048) cxr->cn8, [2048,4096) ehr->en8.
// blocks [0,64) zero rowsum/colsum (64*256 = 16384 = 2N floats); block 0 zeroes out[0].
__global__ __launch_bounds__(256) void prep_kernel(
    const float* __restrict__ CXR, const float* __restrict__ EHR,
    uint32_t* __restrict__ CN8, uint32_t* __restrict__ EN8,
    float* __restrict__ rowsum /* colsum follows contiguously */,
    float* __restrict__ out)
{
    if (blockIdx.x < 64) {
        rowsum[blockIdx.x * 256 + threadIdx.x] = 0.f;
        if (blockIdx.x == 0 && threadIdx.x == 0) out[0] = 0.f;
    }
    const int half = (blockIdx.x >= 2048);
    const float* X = half ? EHR : CXR;
    uint32_t* Y = half ? EN8 : CN8;
    const int row  = (blockIdx.x & 2047) * 4 + (threadIdx.x >> 6);
    const int lane = threadIdx.x & 63;
    const float* xr = X + (size_t)row * DDIM;
    float4 v0 = ((const float4*)xr)[lane];        // elems lane*4   .. +3
    float4 v1 = ((const float4*)xr)[lane + 64];   // elems 256+lane*4 .. +3
    float ss = v0.x*v0.x + v0.y*v0.y + v0.z*v0.z + v0.w*v0.w
             + v1.x*v1.x + v1.y*v1.y + v1.z*v1.z + v1.w*v1.w;
    #pragma unroll
    for (int d = 1; d < 64; d <<= 1) ss += __shfl_xor(ss, d);
    const float sc = 1.0f / fmaxf(sqrtf(ss), 1e-8f);
    uint32_t* yr = Y + (size_t)row * (DDIM / 4);
    int w0 = __builtin_amdgcn_cvt_pk_fp8_f32(v0.x*sc, v0.y*sc, 0, false);
    w0     = __builtin_amdgcn_cvt_pk_fp8_f32(v0.z*sc, v0.w*sc, w0, true);
    int w1 = __builtin_amdgcn_cvt_pk_fp8_f32(v1.x*sc, v1.y*sc, 0, false);
    w1     = __builtin_amdgcn_cvt_pk_fp8_f32(v1.z*sc, v1.w*sc, w1, true);
    yr[lane]      = (uint32_t)w0;   // bytes = elems lane*4..+3 in k order
    yr[lane + 64] = (uint32_t)w1;
}

// -------- fused S = cn·enT fp8 GEMM (16x16x32, double-buffered LDS) + loss ----------
// Round-7 tile geometry (4 waves, wave tile 64x64, acc 4x4 f32x4 in AGPRs) with the
// staging restructured: BKB=64, TWO buffers (2x16 KB, total LDS still 32 KB ->
// occupancy preserved, unlike round 8). Loads for stage s+1 are issued BEFORE
// compute of stage s, so the vmcnt(0) drain at each barrier waits on loads that
// are ~600 cyc old (round 7 issued them 0 cyc before the drain -> 42% MfmaUtil).
// LDS: row r = four 16-B units; unit u at slot u^(r&3). Staging lane l covers
// row l>>2, fetches global unit (l&3)^((l>>2)&3). Fragment read: b128 at u=q,
// slot q^(r&3); lo 8 B -> MFMA window 0, hi -> window 1 of the stage (same
// k-permutation on A and B => dot products unchanged; 8-phase b128 floor => ~0
// excess bank conflicts).
__global__ __launch_bounds__(256, 2) void gemm_loss_kernel(
    const uint8_t* __restrict__ A,   // cn fp8 [N][512 B]
    const uint8_t* __restrict__ B,   // en fp8 [N][512 B]
    const float* __restrict__ temp_p,
    float* __restrict__ rowsum,
    float* __restrict__ colsum,
    float* __restrict__ diagv)
{
    __shared__ uint8_t As[2][TILE * BKB];   // 2 x 8 KB
    __shared__ uint8_t Bs[2][TILE * BKB];   // 2 x 8 KB

    const int tid  = threadIdx.x;
    const int lane = tid & 63;
    const int wv   = tid >> 6;          // wave 0..3
    const int wi   = (wv >> 1) * 64;    // wave row offset in tile
    const int wj   = (wv & 1) * 64;     // wave col offset in tile
    const int lcol = lane & 15;
    const int q    = lane >> 4;

    const int bi = blockIdx.x & (NBLK - 1);
    const int bj = blockIdx.x >> 6;
    const int row0 = bi * TILE;
    const int col0 = bj * TILE;

    // staging geometry: wave wv stages rows [wv*32, wv*32+32), 2 copies x 16 rows
    const int rr = lane >> 2;                 // row within 16-row chunk
    const int gu = (lane & 3) ^ (rr & 3);     // global 16B-unit (swizzle inverse)
    const uint8_t* Agb = A + (size_t)(row0 + wv * 32 + rr) * DDIM + gu * 16;
    const uint8_t* Bgb = B + (size_t)(col0 + wv * 32 + rr) * DDIM + gu * 16;

    // hoisted fragment-read offsets (loop-invariant): [mt|nt]
    int aoff[4], boff[4];
    #pragma unroll
    for (int t = 0; t < 4; ++t) {
        const int ra = wi + t * 16 + lcol;
        const int rb = wj + t * 16 + lcol;
        aoff[t] = ra * BKB + ((q ^ (ra & 3)) * 16);
        boff[t] = rb * BKB + ((q ^ (rb & 3)) * 16);
    }

    f32x4 acc[4][4] = {};

    // prologue: stage 0 into buffer 0
    #pragma unroll
    for (int c = 0; c < 2; ++c) {
        async_copy16(Agb + (size_t)(c * 16) * DDIM, &As[0][(wv * 32 + c * 16) * BKB]);
        async_copy16(Bgb + (size_t)(c * 16) * DDIM, &Bs[0][(wv * 32 + c * 16) * BKB]);
    }
    __syncthreads();

    for (int s = 0; s < NSTG; ++s) {
        const int cur = s & 1;
        // issue next stage into the other buffer BEFORE computing this one
        if (s + 1 < NSTG) {
            const int nxt = (s + 1) & 1;
            const int k0 = (s + 1) * BKB;
            #pragma unroll
            for (int c = 0; c < 2; ++c) {
                async_copy16(Agb + (size_t)(c * 16) * DDIM + k0,
                             &As[nxt][(wv * 32 + c * 16) * BKB]);
                async_copy16(Bgb + (size_t)(c * 16) * DDIM + k0,
                             &Bs[nxt][(wv * 32 + c * 16) * BKB]);
            }
        }
        // compute stage s: 2 K=32 windows from one b128 per row (k-permuted)
        long aflo[4], afhi[4];
        #pragma unroll
        for (int mt = 0; mt < 4; ++mt) {
            v2l a16 = *(const v2l*)&As[cur][aoff[mt]];
            aflo[mt] = a16.x; afhi[mt] = a16.y;
        }
        #pragma unroll
        for (int nt = 0; nt < 4; ++nt) {
            v2l b16 = *(const v2l*)&Bs[cur][boff[nt]];
            #pragma unroll
            for (int mt = 0; mt < 4; ++mt)
                acc[mt][nt] = __builtin_amdgcn_mfma_f32_16x16x32_fp8_fp8(
                    aflo[mt], b16.x, acc[mt][nt], 0, 0, 0);
            #pragma unroll
            for (int mt = 0; mt < 4; ++mt)
                acc[mt][nt] = __builtin_amdgcn_mfma_f32_16x16x32_fp8_fp8(
                    afhi[mt], b16.y, acc[mt][nt], 0, 0, 0);
        }
        __syncthreads();   // drains next-stage loads (aged by this compute) + read fence
    }

    // ---- epilogue: e = exp(s - M), M = 1/T (max possible), diag excluded ----
    const float invT = 1.0f / temp_p[0];
    const float M = invT;

    float rs[4][4];   // per-lane row partials [mt][reg]
    float cs[4];      // per-lane col partials [nt]
    #pragma unroll
    for (int mt = 0; mt < 4; ++mt)
        #pragma unroll
        for (int r = 0; r < 4; ++r) rs[mt][r] = 0.f;
    #pragma unroll
    for (int nt = 0; nt < 4; ++nt) cs[nt] = 0.f;

    #pragma unroll
    for (int mt = 0; mt < 4; ++mt) {
        #pragma unroll
        for (int nt = 0; nt < 4; ++nt) {
            #pragma unroll
            for (int r = 0; r < 4; ++r) {
                // C/D layout: col = lane&15, row = quad*4 + reg  [m89/m91]
                const int gi = row0 + wi + mt * 16 + q * 4 + r;
                const int gj = col0 + wj + nt * 16 + lcol;
                const float sv = acc[mt][nt][r] * invT;
                float e;
                if (gi == gj) { diagv[gi] = sv; e = 0.f; }
                else          { e = __expf(sv - M); }
                rs[mt][r] += e;
                cs[nt]    += e;
            }
        }
    }

    // row sums: reduce across the 16 columns (lane bits 0..3)
    #pragma unroll
    for (int d = 1; d < 16; d <<= 1)
        #pragma unroll
        for (int mt = 0; mt < 4; ++mt)
            #pragma unroll
            for (int r = 0; r < 4; ++r)
                rs[mt][r] += __shfl_xor(rs[mt][r], d);

    // col sums: reduce across the 4 quads (lane bits 4..5)
    #pragma unroll
    for (int d = 16; d < 64; d <<= 1)
        #pragma unroll
        for (int nt = 0; nt < 4; ++nt)
            cs[nt] += __shfl_xor(cs[nt], d);

    if (lcol == 0) {
        #pragma unroll
        for (int mt = 0; mt < 4; ++mt)
            #pragma unroll
            for (int r = 0; r < 4; ++r)
                atomicAdd(&rowsum[row0 + wi + mt * 16 + q * 4 + r], rs[mt][r]);
    }
    if (q == 0) {
        #pragma unroll
        for (int nt = 0; nt < 4; ++nt)
            atomicAdd(&colsum[col0 + wj + nt * 16 + lcol], cs[nt]);
    }
}

// -------- final scalar: loss = mean_i( 2M + log(rowsum_i) + log(colsum_i) - 2*diag_i ) ----
__global__ __launch_bounds__(256) void finalize_kernel(
    const float* __restrict__ rowsum, const float* __restrict__ colsum,
    const float* __restrict__ diagv,  const float* __restrict__ temp_p,
    float* __restrict__ out)
{
    __shared__ float red[4];
    const float M = 1.0f / temp_p[0];
    const int i = blockIdx.x * 256 + threadIdx.x;
    float s = 2.f * M + logf(rowsum[i]) + logf(colsum[i]) - 2.f * diagv[i];
    #pragma unroll
    for (int d = 1; d < 64; d <<= 1) s += __shfl_xor(s, d);
    if ((threadIdx.x & 63) == 0) red[threadIdx.x >> 6] = s;
    __syncthreads();
    if (threadIdx.x == 0)
        atomicAdd(out, (red[0] + red[1] + red[2] + red[3]) / (float)NROWS);
}

extern "C" void kernel_launch(void* const* d_in, const int* in_sizes, int n_in,
                              void* d_out, int out_size, void* d_ws, size_t ws_size,
                              hipStream_t stream) {
    (void)in_sizes; (void)n_in; (void)out_size; (void)ws_size;
    const float* cxr    = (const float*)d_in[0];
    const float* ehr    = (const float*)d_in[1];
    const float* temp_p = (const float*)d_in[2];
    float* out = (float*)d_out;

    // workspace: rowsum[N] | colsum[N] | diag[N] | cn fp8 [N*512B] | en fp8 (~8.1 MB)
    float* rowsum = (float*)d_ws;
    float* colsum = rowsum + NROWS;
    float* diagv  = colsum + NROWS;
    uint32_t* cn8 = (uint32_t*)(diagv + NROWS);            // 16B-aligned (96 KB offset)
    uint32_t* en8 = cn8 + (size_t)NROWS * (DDIM / 4);
    const uint8_t* cnb = (const uint8_t*)cn8;
    const uint8_t* enb = (const uint8_t*)en8;

    prep_kernel<<<4096, 256, 0, stream>>>(cxr, ehr, cn8, en8, rowsum, out);
    gemm_loss_kernel<<<NBLK * NBLK, 256, 0, stream>>>(cnb, enb, temp_p, rowsum, colsum, diagv);
    finalize_kernel<<<NROWS / 256, 256, 0, stream>>>(rowsum, colsum, diagv, temp_p, out);
}